// Round 9
// baseline (358.986 us; speedup 1.0000x reference)
//
#include <hip/hip_runtime.h>

// Problem constants (fixed by reference)
#define NVV 10000    // vertices
#define NKSTEPS 80   // 2560 / 32
#define KSPLIT 40    // ksteps per K-half
#define BN_INV 0.99950037468777316f

#define AS1 __attribute__((address_space(1)))
#define AS3 __attribute__((address_space(3)))

typedef float f32x4 __attribute__((ext_vector_type(4)));
typedef short short8 __attribute__((ext_vector_type(8)));
typedef unsigned short ushort;

// A chunk: [mt 5][sp 2][qk 4][mm 16][kk 8] ushort = 5120 ushorts = 10240 B
#define ACH_USH 5120
#define ACH_B   10240
// W chunk (per kstep,strip): [nt 8][sp 2][q 4][l16 16][kk 8] = 8192 ushorts = 16384 B
#define WCH_B   16384

// ---------------------------------------------------------------------------
// Split a f32 into bf16 (RNE) + f32 remainder (exact).
__device__ __forceinline__ ushort bsplit(float v, float& rem) {
    unsigned u = __float_as_uint(v);
    unsigned r = (u + 0x7fffu + ((u >> 16) & 1u)) & 0xffff0000u;
    rem = v - __uint_as_float(r);
    return (ushort)(r >> 16);
}

// blend 3 gathered float4 rows, split-2 (RNE+RNE) to bf16 planes, store frag layout
__device__ __forceinline__ void interp_store2(ushort* __restrict__ dstp, int it,
                                              const float4& g0, const float4& g1, const float4& g2,
                                              float w0, float w1, float w2) {
    const int m = it >> 3, kq = it & 7;
    const float av[4] = {g0.x, g0.y, g0.z, g0.w};
    const float bv[4] = {g1.x, g1.y, g1.z, g1.w};
    const float cv[4] = {g2.x, g2.y, g2.z, g2.w};
    ushort h1[4], h2[4];
    #pragma unroll
    for (int e = 0; e < 4; ++e) {
        const float vv = w0 * av[e] + w1 * bv[e] + w2 * cv[e];
        float r1, r2;
        h1[e] = bsplit(vv, r1); h2[e] = bsplit(r1, r2);
    }
    const int mt = m >> 4, mm = m & 15, qk = kq >> 1, hf = kq & 1;
    const int o0 = ((mt * 2 + 0) * 4 + qk) * 128 + mm * 8 + hf * 4;   // ushort units
    *(uint2*)(dstp + o0)       = make_uint2((unsigned)h1[0] | ((unsigned)h1[1] << 16),
                                            (unsigned)h1[2] | ((unsigned)h1[3] << 16));
    *(uint2*)(dstp + o0 + 512) = make_uint2((unsigned)h2[0] | ((unsigned)h2[1] << 16),
                                            (unsigned)h2[2] | ((unsigned)h2[3] << 16));
}

// ---------------------------------------------------------------------------
// W global layout (per stage): [kstep 80][strip 4] chunks of 16384 B.
// w = w1 + w2 (2 RNE planes; residual <= 2^-16 relative).
__global__ void build_w_kernel(const float* __restrict__ t1,
                               const float* __restrict__ t2,
                               ushort* __restrict__ W1g,
                               ushort* __restrict__ W2g) {
    const int k = blockIdx.x;       // 0..2559
    const int n = threadIdx.x;      // 0..511
    const float* T  = blockIdx.y ? t2 : t1;
    ushort*      Wg = blockIdx.y ? W2g : W1g;
    const int r = k >> 9, a = (k >> 6) & 7, c = k & 63;
    const int o = n >> 6, t = n & 63;
    const float w = T[((t * 5 + r) * 8 + ((o + a) & 7)) * 64 + c];
    float r1, r2;
    const ushort h1 = bsplit(w, r1);
    const ushort h2 = bsplit(r1, r2);
    const int kstep = k >> 5, kw = k & 31, q = kw >> 3, kk = kw & 7;
    const int strip = n >> 7, nl = n & 127, nt = nl >> 4, l16 = nl & 15;
    const size_t base = (size_t)(kstep * 4 + strip) * 8192;
    const int off = ((nt * 2 + 0) * 4 + q) * 128 + l16 * 8 + kk;
    Wg[base + off]       = h1;      // sp stride = 512 ushorts
    Wg[base + off + 512] = h2;
}

// ---------------------------------------------------------------------------
// Materialize interp (gather+blend) as 2 RNE bf16 split planes, A-frag layout.
// One block per (mg-local, kstep) chunk of 10240 B.
__global__ void interp_kernel(const float* __restrict__ src,
                              const int*   __restrict__ bc_idx,
                              const float* __restrict__ bc_w,
                              ushort*      __restrict__ Ag,
                              int mg0) {
    const int cid = blockIdx.x;            // pass-local chunk id
    const int mgl = cid / NKSTEPS;
    const int ks  = cid % NKSTEPS;
    const int mg  = mg0 + mgl;
    const int x   = threadIdx.x;
    ushort* chunk = Ag + (size_t)cid * ACH_USH;
    const int ra = ks >> 1;
    #pragma unroll
    for (int s = 0; s < 3; ++s) {
        const int it = x + 256 * s;        // 640 items = 80 rows x 8 k-quads
        if (it < 640) {
            const int m = it >> 3, kq = it & 7;
            const int v = mg * 80 + m;
            const int*   ip = bc_idx + v * 120 + ra * 3;
            const float* wp = bc_w  + v * 120 + ra * 3;
            const int c0 = (ks & 1) * 32 + kq * 4;
            const float4 g0 = *(const float4*)(src + (size_t)ip[0] * 64 + c0);
            const float4 g1 = *(const float4*)(src + (size_t)ip[1] * 64 + c0);
            const float4 g2 = *(const float4*)(src + (size_t)ip[2] * 64 + c0);
            interp_store2(chunk, it, g0, g1, g2, wp[0], wp[1], wp[2]);
        }
    }
}

// ---------------------------------------------------------------------------
// 3-product split MFMA GEMM, K-SPLIT in half: block = 80 rows x 128 cols x
// K=1280 (40 ksteps). Grid ~1000 -> 3 blocks/CU co-resident with independent
// barrier phases, so one block's LDS burst overlaps another's MFMA window
// (fixes the phase-serialization that capped R8 at 86 us).
// Partials go to S1/S2 (no bias); pool combines. XCD-pinned by mg.
__global__ __launch_bounds__(256, 3)
void gemm_kernel(const ushort* __restrict__ Ag,
                 const ushort* __restrict__ Wg,
                 float*       __restrict__ S1,       // (V,512) partial, khalf 0
                 float*       __restrict__ S2,       // (V,512) partial, khalf 1
                 int mg0, int Pp, int mpx) {
    __shared__ ushort sW[2][8192];    // 2 x 16384 B
    __shared__ ushort sA[2][ACH_USH]; // 2 x 10240 B   total 53248 B -> 3 blk/CU
    const int x = threadIdx.x;
    const int b = blockIdx.x;
    const int xcd   = b & 7;
    const int rest  = b >> 3;
    const int khalf = rest & 1;
    const int strip = (rest >> 1) & 3;
    const int mgl_l = rest >> 3;
    const int mg_local = xcd * mpx + mgl_l;
    if (mg_local >= Pp) return;
    const int mg    = mg0 + mg_local;
    const int Mbase = mg * 80;
    const int ks0   = khalf * KSPLIT;
    const int wj  = x >> 6;
    const int l16 = x & 15;
    const int q   = (x & 63) >> 4;

    f32x4 d[5][2] = {};               // 40 f32 accumulators

    const char* gWb = (const char*)Wg;
    const char* gAb = (const char*)Ag + (size_t)mg_local * NKSTEPS * ACH_B;

    // ---- prologue: DMA W(ks0), A(ks0) into buffer 0 ----
    {
        const char* gw = gWb + (size_t)(ks0 * 4 + strip) * WCH_B;
        char*       lw = (char*)sW[0];
        #pragma unroll
        for (int j = 0; j < 4; ++j)
            __builtin_amdgcn_global_load_lds((AS1 const void*)(gw + (x + 256 * j) * 16),
                                             (AS3 void*)(lw + (x + 256 * j) * 16), 16, 0, 0);
        const char* ga = gAb + (size_t)ks0 * ACH_B;
        char*       la = (char*)sA[0];
        #pragma unroll
        for (int j = 0; j < 3; ++j) {
            const int it = x + 256 * j;
            if (it < 640)
                __builtin_amdgcn_global_load_lds((AS1 const void*)(ga + it * 16),
                                                 (AS3 void*)(la + it * 16), 16, 0, 0);
        }
    }
    __syncthreads();

    // ---- main loop: 1 barrier per kstep, 40 ksteps ----
    for (int ki = 0; ki < KSPLIT; ++ki) {
        const int ks = ks0 + ki;
        const int cur = ki & 1, nxt = cur ^ 1;
        if (ki + 1 < KSPLIT) {
            const char* gw = gWb + (size_t)((ks + 1) * 4 + strip) * WCH_B;
            char*       lw = (char*)sW[nxt];
            #pragma unroll
            for (int j = 0; j < 4; ++j)
                __builtin_amdgcn_global_load_lds((AS1 const void*)(gw + (x + 256 * j) * 16),
                                                 (AS3 void*)(lw + (x + 256 * j) * 16), 16, 0, 0);
            const char* ga = gAb + (size_t)(ks + 1) * ACH_B;
            char*       la = (char*)sA[nxt];
            #pragma unroll
            for (int j = 0; j < 3; ++j) {
                const int it = x + 256 * j;
                if (it < 640)
                    __builtin_amdgcn_global_load_lds((AS1 const void*)(ga + it * 16),
                                                     (AS3 void*)(la + it * 16), 16, 0, 0);
            }
        }

        // MFMA: 3 products {a1w1, a1w2, a2w1} per (mt, nt)
        short8 w1f[2], w2f[2];
        #pragma unroll
        for (int nt = 0; nt < 2; ++nt) {
            const int ntg = 2 * wj + nt;
            w1f[nt] = *(const short8*)(sW[cur] + ((ntg * 2 + 0) * 4 + q) * 128 + l16 * 8);
            w2f[nt] = *(const short8*)(sW[cur] + ((ntg * 2 + 1) * 4 + q) * 128 + l16 * 8);
        }
        #pragma unroll
        for (int mt = 0; mt < 5; ++mt) {
            const short8 a1 = *(const short8*)(sA[cur] + ((mt * 2 + 0) * 4 + q) * 128 + l16 * 8);
            const short8 a2 = *(const short8*)(sA[cur] + ((mt * 2 + 1) * 4 + q) * 128 + l16 * 8);
            #pragma unroll
            for (int nt = 0; nt < 2; ++nt) {
                d[mt][nt] = __builtin_amdgcn_mfma_f32_16x16x32_bf16(a1, w1f[nt], d[mt][nt], 0, 0, 0);
                d[mt][nt] = __builtin_amdgcn_mfma_f32_16x16x32_bf16(a1, w2f[nt], d[mt][nt], 0, 0, 0);
                d[mt][nt] = __builtin_amdgcn_mfma_f32_16x16x32_bf16(a2, w1f[nt], d[mt][nt], 0, 0, 0);
            }
        }
        __syncthreads();   // drains DMA(ki+1) (covered by MFMA phase) + closes reads
    }

    // ---- epilogue: store raw partial (no bias) to this half's S buffer ----
    float* Sh = khalf ? S2 : S1;
    #pragma unroll
    for (int mt = 0; mt < 5; ++mt) {
        #pragma unroll
        for (int nt = 0; nt < 2; ++nt) {
            #pragma unroll
            for (int r = 0; r < 4; ++r) {
                const int mglob = Mbase + mt * 16 + q * 4 + r;
                const int nglob = strip * 128 + wj * 32 + nt * 16 + l16;
                Sh[(size_t)mglob * 512 + nglob] = d[mt][nt][r];
            }
        }
    }
}

// ---------------------------------------------------------------------------
// Combine partials + bias, angular max-pool + BN (+residual) + ReLU.
// One wave per vertex: lane = t, loop over the 8 o's; butterfly norm reduce.
template<bool RES>
__global__ void pool_kernel(const float* __restrict__ S1,
                            const float* __restrict__ S2,
                            const float* __restrict__ bias,
                            const float* __restrict__ gamma,
                            const float* __restrict__ beta,
                            const float* __restrict__ resid,
                            float*       __restrict__ dst) {
    const int w = threadIdx.x >> 6;           // wave 0..3
    const int t = threadIdx.x & 63;
    const int v = blockIdx.x * 4 + w;         // grid 2500 -> 10000 vertices
    const float bt = bias[t];
    float vals[8], n2[8];
    #pragma unroll
    for (int o = 0; o < 8; ++o) {
        const size_t idx = (size_t)v * 512 + o * 64 + t;
        const float val = S1[idx] + S2[idx] + bt;
        vals[o] = val;
        float s = val * val;
        #pragma unroll
        for (int off = 1; off < 64; off <<= 1) s += __shfl_xor(s, off, 64);
        n2[o] = s;
    }
    int bj = 0; float bv = n2[0];
    #pragma unroll
    for (int j = 1; j < 8; ++j) {
        if (n2[j] > bv) { bv = n2[j]; bj = j; }   // first-max tie-break (jnp.argmax)
    }
    float val = vals[0];
    #pragma unroll
    for (int j = 1; j < 8; ++j) val = (bj == j) ? vals[j] : val;
    float r = gamma[t] * (val * BN_INV) + beta[t];
    if (RES) r += resid[(size_t)v * 64 + t];
    dst[(size_t)v * 64 + t] = fmaxf(r, 0.0f);
}

// ---------------------------------------------------------------------------
extern "C" void kernel_launch(void* const* d_in, const int* in_sizes, int n_in,
                              void* d_out, int out_size, void* d_ws, size_t ws_size,
                              hipStream_t stream) {
    const float* signal = (const float*)d_in[0];
    const float* bc_w   = (const float*)d_in[1];
    const float* t1     = (const float*)d_in[2];
    const float* bias1  = (const float*)d_in[3];
    const float* gamma1 = (const float*)d_in[4];
    const float* beta1  = (const float*)d_in[5];
    const float* t2     = (const float*)d_in[6];
    const float* bias2  = (const float*)d_in[7];
    const float* gamma2 = (const float*)d_in[8];
    const float* beta2  = (const float*)d_in[9];
    const int*   bc_idx = (const int*)d_in[10];

    // ws: W1g 5.24 | W2g 5.24 | S1 20.48 | S2 20.48 | s1 2.56 | Ag (rest) MB
    const size_t WSTG = (size_t)NKSTEPS * 4 * 8192;       // ushorts per stage W
    ushort* W1g = (ushort*)d_ws;
    ushort* W2g = W1g + WSTG;
    float* S1 = (float*)(W2g + WSTG);
    float* S2 = S1 + (size_t)NVV * 512;
    float* s1 = S2 + (size_t)NVV * 512;
    ushort* Ag = (ushort*)(s1 + (size_t)NVV * 64);
    float* out = (float*)d_out;

    // pass-chunk the materialized interp to fit ws_size (full A = 102.4 MB)
    const size_t used  = (size_t)((char*)Ag - (char*)d_ws);
    const size_t avail = ws_size > used ? ws_size - used : 0;
    int P = (int)(avail / ((size_t)NKSTEPS * ACH_B));     // mgs per pass
    if (P > 125) P = 125;
    if (P < 1)  P = 1;

    build_w_kernel<<<dim3(2560, 2), 512, 0, stream>>>(t1, t2, W1g, W2g);

    // stage 1
    for (int mg0 = 0; mg0 < 125; mg0 += P) {
        const int Pp  = (125 - mg0 < P) ? (125 - mg0) : P;
        const int mpx = (Pp + 7) / 8;
        interp_kernel<<<Pp * NKSTEPS, 256, 0, stream>>>(signal, bc_idx, bc_w, Ag, mg0);
        gemm_kernel<<<64 * mpx, 256, 0, stream>>>(Ag, W1g, S1, S2, mg0, Pp, mpx);
    }
    pool_kernel<false><<<2500, 256, 0, stream>>>(S1, S2, bias1, gamma1, beta1, nullptr, s1);

    // stage 2
    for (int mg0 = 0; mg0 < 125; mg0 += P) {
        const int Pp  = (125 - mg0 < P) ? (125 - mg0) : P;
        const int mpx = (Pp + 7) / 8;
        interp_kernel<<<Pp * NKSTEPS, 256, 0, stream>>>(s1, bc_idx, bc_w, Ag, mg0);
        gemm_kernel<<<64 * mpx, 256, 0, stream>>>(Ag, W2g, S1, S2, mg0, Pp, mpx);
    }
    pool_kernel<true><<<2500, 256, 0, stream>>>(S1, S2, bias2, gamma2, beta2, signal, out);
}

// Round 11
// 333.319 us; speedup vs baseline: 1.0770x; 1.0770x over previous
//
#include <hip/hip_runtime.h>

// Problem constants (fixed by reference)
#define NVV 10000    // vertices
#define NKSTEPS 80   // 2560 / 32
#define BN_INV 0.99950037468777316f

#define AS1 __attribute__((address_space(1)))
#define AS3 __attribute__((address_space(3)))

typedef float f32x4 __attribute__((ext_vector_type(4)));
typedef short short8 __attribute__((ext_vector_type(8)));
typedef unsigned short ushort;

// A chunk: [mt 5][sp 2][qk 4][mm 16][kk 8] ushort = 5120 ushorts = 10240 B
// A fragment (mt,sp) = contiguous 1024 B; lane i holds bytes [16i,16i+16).
#define ACH_USH 5120
#define ACH_B   10240
// W chunk (per kstep,strip): [nt 8][sp 2][q 4][l16 16][kk 8] = 16384 B
#define WCH_B   16384

// ---------------------------------------------------------------------------
// Split a f32 into bf16 (RNE) + f32 remainder (exact).
__device__ __forceinline__ ushort bsplit(float v, float& rem) {
    unsigned u = __float_as_uint(v);
    unsigned r = (u + 0x7fffu + ((u >> 16) & 1u)) & 0xffff0000u;
    rem = v - __uint_as_float(r);
    return (ushort)(r >> 16);
}

// blend 3 gathered float4 rows, split-2 (RNE+RNE) to bf16 planes, store frag layout
__device__ __forceinline__ void interp_store2(ushort* __restrict__ dstp, int it,
                                              const float4& g0, const float4& g1, const float4& g2,
                                              float w0, float w1, float w2) {
    const int m = it >> 3, kq = it & 7;
    const float av[4] = {g0.x, g0.y, g0.z, g0.w};
    const float bv[4] = {g1.x, g1.y, g1.z, g1.w};
    const float cv[4] = {g2.x, g2.y, g2.z, g2.w};
    ushort h1[4], h2[4];
    #pragma unroll
    for (int e = 0; e < 4; ++e) {
        const float vv = w0 * av[e] + w1 * bv[e] + w2 * cv[e];
        float r1, r2;
        h1[e] = bsplit(vv, r1); h2[e] = bsplit(r1, r2);
    }
    const int mt = m >> 4, mm = m & 15, qk = kq >> 1, hf = kq & 1;
    const int o0 = ((mt * 2 + 0) * 4 + qk) * 128 + mm * 8 + hf * 4;   // ushort units
    *(uint2*)(dstp + o0)       = make_uint2((unsigned)h1[0] | ((unsigned)h1[1] << 16),
                                            (unsigned)h1[2] | ((unsigned)h1[3] << 16));
    *(uint2*)(dstp + o0 + 512) = make_uint2((unsigned)h2[0] | ((unsigned)h2[1] << 16),
                                            (unsigned)h2[2] | ((unsigned)h2[3] << 16));
}

// ---------------------------------------------------------------------------
// W global layout (per stage): [kstep 80][strip 4] chunks of 16384 B.
// w = w1 + w2 (2 RNE planes; residual <= 2^-16 relative).
__global__ void build_w_kernel(const float* __restrict__ t1,
                               const float* __restrict__ t2,
                               ushort* __restrict__ W1g,
                               ushort* __restrict__ W2g) {
    const int k = blockIdx.x;       // 0..2559
    const int n = threadIdx.x;      // 0..511
    const float* T  = blockIdx.y ? t2 : t1;
    ushort*      Wg = blockIdx.y ? W2g : W1g;
    const int r = k >> 9, a = (k >> 6) & 7, c = k & 63;
    const int o = n >> 6, t = n & 63;
    const float w = T[((t * 5 + r) * 8 + ((o + a) & 7)) * 64 + c];
    float r1, r2;
    const ushort h1 = bsplit(w, r1);
    const ushort h2 = bsplit(r1, r2);
    const int kstep = k >> 5, kw = k & 31, q = kw >> 3, kk = kw & 7;
    const int strip = n >> 7, nl = n & 127, nt = nl >> 4, l16 = nl & 15;
    const size_t base = (size_t)(kstep * 4 + strip) * 8192;
    const int off = ((nt * 2 + 0) * 4 + q) * 128 + l16 * 8 + kk;
    Wg[base + off]       = h1;      // sp stride = 512 ushorts
    Wg[base + off + 512] = h2;
}

// ---------------------------------------------------------------------------
// Materialize interp (gather+blend) as 2 RNE bf16 split planes, A-frag layout.
// One block per (mg-local, kstep) chunk of 10240 B.
__global__ void interp_kernel(const float* __restrict__ src,
                              const int*   __restrict__ bc_idx,
                              const float* __restrict__ bc_w,
                              ushort*      __restrict__ Ag,
                              int mg0) {
    const int cid = blockIdx.x;            // pass-local chunk id
    const int mgl = cid / NKSTEPS;
    const int ks  = cid % NKSTEPS;
    const int mg  = mg0 + mgl;
    const int x   = threadIdx.x;
    ushort* chunk = Ag + (size_t)cid * ACH_USH;
    const int ra = ks >> 1;
    #pragma unroll
    for (int s = 0; s < 3; ++s) {
        const int it = x + 256 * s;        // 640 items = 80 rows x 8 k-quads
        if (it < 640) {
            const int m = it >> 3, kq = it & 7;
            const int v = mg * 80 + m;
            const int*   ip = bc_idx + v * 120 + ra * 3;
            const float* wp = bc_w  + v * 120 + ra * 3;
            const int c0 = (ks & 1) * 32 + kq * 4;
            const float4 g0 = *(const float4*)(src + (size_t)ip[0] * 64 + c0);
            const float4 g1 = *(const float4*)(src + (size_t)ip[1] * 64 + c0);
            const float4 g2 = *(const float4*)(src + (size_t)ip[2] * 64 + c0);
            interp_store2(chunk, it, g0, g1, g2, wp[0], wp[1], wp[2]);
        }
    }
}

// ---------------------------------------------------------------------------
// 3-product split MFMA GEMM, BARRIER-FREE K-loop: A and W fragments are
// loaded directly into VGPRs (each frag = contiguous 1 KB, lane*16B) from
// the XCD-pinned L2, register-double-buffered. Loads for kstep+1 are in
// flight while MFMAs consume kstep => compiler emits fine-grained
// s_waitcnt vmcnt(N>0) (AITER pattern), no __syncthreads in the loop.
// Block = 80 rows x 128 cols; 4 waves split N (wave wj -> cols 32wj..+32).
#define GEMM_LOADS(AB, WB, KS)                                              \
    if ((KS) < NKSTEPS) {                                                   \
        const AS1 char* an = aBase + (size_t)(KS) * ACH_B;                  \
        const AS1 char* wn = wBase + (size_t)(KS) * (4 * WCH_B);            \
        _Pragma("unroll")                                                   \
        for (int f = 0; f < 10; ++f)                                        \
            AB[f] = *(const AS1 short8*)(an + f * 1024);                    \
        _Pragma("unroll")                                                   \
        for (int f = 0; f < 4; ++f)                                         \
            WB[f] = *(const AS1 short8*)(wn + f * 1024);                    \
    }

#define GEMM_MFMAS(AB, WB)                                                  \
    _Pragma("unroll")                                                       \
    for (int mt = 0; mt < 5; ++mt) {                                        \
        _Pragma("unroll")                                                   \
        for (int nt = 0; nt < 2; ++nt) {                                    \
            d[mt][nt] = __builtin_amdgcn_mfma_f32_16x16x32_bf16(            \
                AB[mt * 2 + 0], WB[nt * 2 + 0], d[mt][nt], 0, 0, 0);        \
            d[mt][nt] = __builtin_amdgcn_mfma_f32_16x16x32_bf16(            \
                AB[mt * 2 + 0], WB[nt * 2 + 1], d[mt][nt], 0, 0, 0);        \
            d[mt][nt] = __builtin_amdgcn_mfma_f32_16x16x32_bf16(            \
                AB[mt * 2 + 1], WB[nt * 2 + 0], d[mt][nt], 0, 0, 0);        \
        }                                                                   \
    }

__global__ __launch_bounds__(256, 2)
void gemm_kernel(const ushort* __restrict__ Ag,
                 const ushort* __restrict__ Wg,
                 const float* __restrict__ bias,     // (64)
                 float*       __restrict__ S,        // (V,512)
                 float*       __restrict__ normsq,   // (V,8)
                 int mg0, int Pp, int mpx) {
    __shared__ float sN[4 * 80];      // epilogue-only LDS (1280 B)
    const int x = threadIdx.x;
    const int b = blockIdx.x;
    const int xcd  = b & 7;
    const int rest = b >> 3;
    const int strip = rest & 3;
    const int mgl_l = rest >> 2;
    const int mg_local = xcd * mpx + mgl_l;
    if (mg_local >= Pp) return;
    const int mg    = mg0 + mg_local;
    const int Mbase = mg * 80;
    const int wj   = x >> 6;
    const int lane = x & 63;
    const int l16  = lane & 15;
    const int q    = lane >> 4;

    f32x4 d[5][2] = {};               // 40 f32 accumulators

    // Per-lane fragment base pointers (frag = contiguous 1 KB, lane*16 B).
    const AS1 char* aBase = (const AS1 char*)Ag
        + (size_t)mg_local * NKSTEPS * ACH_B + lane * 16;
    const AS1 char* wBase = (const AS1 char*)Wg
        + (size_t)strip * WCH_B + (size_t)wj * 4096 + lane * 16;

    short8 A0[10], W0[4], A1[10], W1[4];

    GEMM_LOADS(A0, W0, 0);            // prologue: kstep 0 -> buffer 0

    for (int ks2 = 0; ks2 < NKSTEPS; ks2 += 2) {
        GEMM_LOADS(A1, W1, ks2 + 1);  // in-flight while consuming buf 0
        GEMM_MFMAS(A0, W0);
        GEMM_LOADS(A0, W0, ks2 + 2);  // in-flight while consuming buf 1
        GEMM_MFMAS(A1, W1);
    }

    // ---- epilogue: +bias, store S, norms^2 -> normsq ----
    float bs[2];
    #pragma unroll
    for (int nt = 0; nt < 2; ++nt)
        bs[nt] = bias[(32 * wj + 16 * nt + l16) & 63];

    float p[5][4];
    #pragma unroll
    for (int mt = 0; mt < 5; ++mt)
        #pragma unroll
        for (int r = 0; r < 4; ++r) p[mt][r] = 0.0f;

    #pragma unroll
    for (int mt = 0; mt < 5; ++mt) {
        #pragma unroll
        for (int nt = 0; nt < 2; ++nt) {
            #pragma unroll
            for (int r = 0; r < 4; ++r) {
                const float val = d[mt][nt][r] + bs[nt];
                const int mglob = Mbase + mt * 16 + q * 4 + r;
                const int nglob = strip * 128 + wj * 32 + nt * 16 + l16;
                S[(size_t)mglob * 512 + nglob] = val;
                p[mt][r] += val * val;
            }
        }
    }
    #pragma unroll
    for (int mt = 0; mt < 5; ++mt)
        #pragma unroll
        for (int r = 0; r < 4; ++r) {
            float v = p[mt][r];
            v += __shfl_xor(v, 1, 64);
            v += __shfl_xor(v, 2, 64);
            v += __shfl_xor(v, 4, 64);
            v += __shfl_xor(v, 8, 64);
            p[mt][r] = v;
        }
    if (l16 == 0) {
        #pragma unroll
        for (int mt = 0; mt < 5; ++mt)
            #pragma unroll
            for (int r = 0; r < 4; ++r)
                sN[wj * 80 + mt * 16 + q * 4 + r] = p[mt][r];
    }
    __syncthreads();
    if (x < 80) {
        const int v = Mbase + x;
        // waves 0,1 -> o = strip*2 ; waves 2,3 -> o = strip*2+1
        normsq[(size_t)v * 8 + strip * 2]     = sN[0 * 80 + x] + sN[1 * 80 + x];
        normsq[(size_t)v * 8 + strip * 2 + 1] = sN[2 * 80 + x] + sN[3 * 80 + x];
    }
}

// ---------------------------------------------------------------------------
// Angular max-pool + BN (+residual) + ReLU. One thread per (v, t).
template<bool RES>
__global__ void pool_kernel(const float* __restrict__ S,
                            const float* __restrict__ normsq,
                            const float* __restrict__ gamma,
                            const float* __restrict__ beta,
                            const float* __restrict__ resid,
                            float*       __restrict__ dst) {
    const int gid = blockIdx.x * 256 + threadIdx.x;   // 640000 = 2500*256
    const int v = gid >> 6, t = gid & 63;
    const float* nv = normsq + (size_t)v * 8;
    float bv = nv[0];
    int   bj = 0;
    #pragma unroll
    for (int j = 1; j < 8; ++j) {
        const float tv = nv[j];
        if (tv > bv) { bv = tv; bj = j; }   // first-max tie-break (jnp.argmax)
    }
    const float val = S[(size_t)v * 512 + bj * 64 + t];
    float r = gamma[t] * (val * BN_INV) + beta[t];
    if (RES) r += resid[(size_t)v * 64 + t];
    dst[(size_t)v * 64 + t] = fmaxf(r, 0.0f);
}

// ---------------------------------------------------------------------------
extern "C" void kernel_launch(void* const* d_in, const int* in_sizes, int n_in,
                              void* d_out, int out_size, void* d_ws, size_t ws_size,
                              hipStream_t stream) {
    const float* signal = (const float*)d_in[0];
    const float* bc_w   = (const float*)d_in[1];
    const float* t1     = (const float*)d_in[2];
    const float* bias1  = (const float*)d_in[3];
    const float* gamma1 = (const float*)d_in[4];
    const float* beta1  = (const float*)d_in[5];
    const float* t2     = (const float*)d_in[6];
    const float* bias2  = (const float*)d_in[7];
    const float* gamma2 = (const float*)d_in[8];
    const float* beta2  = (const float*)d_in[9];
    const int*   bc_idx = (const int*)d_in[10];

    // ws: W1g 5.24 MB | W2g 5.24 MB | S 20.48 MB | normsq 0.32 MB | s1 2.56 MB | Ag (rest)
    const size_t WSTG = (size_t)NKSTEPS * 4 * 8192;       // ushorts per stage W
    ushort* W1g = (ushort*)d_ws;
    ushort* W2g = W1g + WSTG;
    float* S      = (float*)(W2g + WSTG);
    float* normsq = S + (size_t)NVV * 512;
    float* s1     = normsq + (size_t)NVV * 8;
    ushort* Ag    = (ushort*)(s1 + (size_t)NVV * 64);
    float* out    = (float*)d_out;

    // pass-chunk the materialized interp to fit ws_size (full A = 102.4 MB)
    const size_t used  = (size_t)((char*)Ag - (char*)d_ws);
    const size_t avail = ws_size > used ? ws_size - used : 0;
    int P = (int)(avail / ((size_t)NKSTEPS * ACH_B));     // mgs per pass
    if (P > 125) P = 125;
    if (P < 1)  P = 1;

    build_w_kernel<<<dim3(2560, 2), 512, 0, stream>>>(t1, t2, W1g, W2g);

    // stage 1
    for (int mg0 = 0; mg0 < 125; mg0 += P) {
        const int Pp  = (125 - mg0 < P) ? (125 - mg0) : P;
        const int mpx = (Pp + 7) / 8;
        interp_kernel<<<Pp * NKSTEPS, 256, 0, stream>>>(signal, bc_idx, bc_w, Ag, mg0);
        gemm_kernel<<<32 * mpx, 256, 0, stream>>>(Ag, W1g, bias1, S, normsq, mg0, Pp, mpx);
    }
    pool_kernel<false><<<2500, 256, 0, stream>>>(S, normsq, gamma1, beta1, nullptr, s1);

    // stage 2
    for (int mg0 = 0; mg0 < 125; mg0 += P) {
        const int Pp  = (125 - mg0 < P) ? (125 - mg0) : P;
        const int mpx = (Pp + 7) / 8;
        interp_kernel<<<Pp * NKSTEPS, 256, 0, stream>>>(s1, bc_idx, bc_w, Ag, mg0);
        gemm_kernel<<<32 * mpx, 256, 0, stream>>>(Ag, W2g, bias2, S, normsq, mg0, Pp, mpx);
    }
    pool_kernel<true><<<2500, 256, 0, stream>>>(S, normsq, gamma2, beta2, signal, out);
}

// Round 12
// 314.303 us; speedup vs baseline: 1.1422x; 1.0605x over previous
//
#include <hip/hip_runtime.h>

// Problem constants (fixed by reference)
#define NVV 10000    // vertices
#define NKSTEPS 80   // 2560 / 32
#define KSPLIT 40    // ksteps per K-half
#define BN_INV 0.99950037468777316f

#define AS1 __attribute__((address_space(1)))
#define AS3 __attribute__((address_space(3)))

typedef float f32x4 __attribute__((ext_vector_type(4)));
typedef short short8 __attribute__((ext_vector_type(8)));
typedef unsigned short ushort;

// A chunk: [mt 5][sp 2][qk 4][mm 16][kk 8] ushort = 5120 ushorts = 10240 B
// A fragment (mt,sp) = contiguous 1024 B; lane i holds bytes [16i,16i+16).
#define ACH_USH 5120
#define ACH_B   10240
// W chunk (per kstep,strip): [nt 8][sp 2][q 4][l16 16][kk 8] = 16384 B
#define WCH_B   16384

// ---------------------------------------------------------------------------
// Split a f32 into bf16 (RNE) + f32 remainder (exact).
__device__ __forceinline__ ushort bsplit(float v, float& rem) {
    unsigned u = __float_as_uint(v);
    unsigned r = (u + 0x7fffu + ((u >> 16) & 1u)) & 0xffff0000u;
    rem = v - __uint_as_float(r);
    return (ushort)(r >> 16);
}

// blend 3 gathered float4 rows, split-2 (RNE+RNE) to bf16 planes, store frag layout
__device__ __forceinline__ void interp_store2(ushort* __restrict__ dstp, int it,
                                              const float4& g0, const float4& g1, const float4& g2,
                                              float w0, float w1, float w2) {
    const int m = it >> 3, kq = it & 7;
    const float av[4] = {g0.x, g0.y, g0.z, g0.w};
    const float bv[4] = {g1.x, g1.y, g1.z, g1.w};
    const float cv[4] = {g2.x, g2.y, g2.z, g2.w};
    ushort h1[4], h2[4];
    #pragma unroll
    for (int e = 0; e < 4; ++e) {
        const float vv = w0 * av[e] + w1 * bv[e] + w2 * cv[e];
        float r1, r2;
        h1[e] = bsplit(vv, r1); h2[e] = bsplit(r1, r2);
    }
    const int mt = m >> 4, mm = m & 15, qk = kq >> 1, hf = kq & 1;
    const int o0 = ((mt * 2 + 0) * 4 + qk) * 128 + mm * 8 + hf * 4;   // ushort units
    *(uint2*)(dstp + o0)       = make_uint2((unsigned)h1[0] | ((unsigned)h1[1] << 16),
                                            (unsigned)h1[2] | ((unsigned)h1[3] << 16));
    *(uint2*)(dstp + o0 + 512) = make_uint2((unsigned)h2[0] | ((unsigned)h2[1] << 16),
                                            (unsigned)h2[2] | ((unsigned)h2[3] << 16));
}

// ---------------------------------------------------------------------------
// W global layout (per stage): [kstep 80][strip 4] chunks of 16384 B.
// w = w1 + w2 (2 RNE planes; residual <= 2^-16 relative).
__global__ void build_w_kernel(const float* __restrict__ t1,
                               const float* __restrict__ t2,
                               ushort* __restrict__ W1g,
                               ushort* __restrict__ W2g) {
    const int k = blockIdx.x;       // 0..2559
    const int n = threadIdx.x;      // 0..511
    const float* T  = blockIdx.y ? t2 : t1;
    ushort*      Wg = blockIdx.y ? W2g : W1g;
    const int r = k >> 9, a = (k >> 6) & 7, c = k & 63;
    const int o = n >> 6, t = n & 63;
    const float w = T[((t * 5 + r) * 8 + ((o + a) & 7)) * 64 + c];
    float r1, r2;
    const ushort h1 = bsplit(w, r1);
    const ushort h2 = bsplit(r1, r2);
    const int kstep = k >> 5, kw = k & 31, q = kw >> 3, kk = kw & 7;
    const int strip = n >> 7, nl = n & 127, nt = nl >> 4, l16 = nl & 15;
    const size_t base = (size_t)(kstep * 4 + strip) * 8192;
    const int off = ((nt * 2 + 0) * 4 + q) * 128 + l16 * 8 + kk;
    Wg[base + off]       = h1;      // sp stride = 512 ushorts
    Wg[base + off + 512] = h2;
}

// ---------------------------------------------------------------------------
// Materialize interp (gather+blend) as 2 RNE bf16 split planes, A-frag layout.
// One block per (mg-local, kstep) chunk of 10240 B.
__global__ void interp_kernel(const float* __restrict__ src,
                              const int*   __restrict__ bc_idx,
                              const float* __restrict__ bc_w,
                              ushort*      __restrict__ Ag,
                              int mg0) {
    const int cid = blockIdx.x;            // pass-local chunk id
    const int mgl = cid / NKSTEPS;
    const int ks  = cid % NKSTEPS;
    const int mg  = mg0 + mgl;
    const int x   = threadIdx.x;
    ushort* chunk = Ag + (size_t)cid * ACH_USH;
    const int ra = ks >> 1;
    #pragma unroll
    for (int s = 0; s < 3; ++s) {
        const int it = x + 256 * s;        // 640 items = 80 rows x 8 k-quads
        if (it < 640) {
            const int m = it >> 3, kq = it & 7;
            const int v = mg * 80 + m;
            const int*   ip = bc_idx + v * 120 + ra * 3;
            const float* wp = bc_w  + v * 120 + ra * 3;
            const int c0 = (ks & 1) * 32 + kq * 4;
            const float4 g0 = *(const float4*)(src + (size_t)ip[0] * 64 + c0);
            const float4 g1 = *(const float4*)(src + (size_t)ip[1] * 64 + c0);
            const float4 g2 = *(const float4*)(src + (size_t)ip[2] * 64 + c0);
            interp_store2(chunk, it, g0, g1, g2, wp[0], wp[1], wp[2]);
        }
    }
}

// ---------------------------------------------------------------------------
// 3-product split MFMA GEMM — FULL-N blocks, barrier-free, register dbuf.
// Block = 80 rows x 512 cols (ALL strips); wave wj owns strip wj (128 cols).
// Per kstep per wave: 10 A-frag + 16 W-frag coalesced loads (26 KB) feed
// 120 MFMAs -> 216 B/MFMA: MFMA-bound, no intra-block duplication, no LDS,
// no __syncthreads. K split in half (grid 250 = 125 mg x 2 khalf, ~1/CU);
// partials to S1/S2, combined in pool (R9-proven, ulp-neutral).
#define GEMM_LOADS(AB, WB, KS)                                              \
    if ((KS) < ksend) {                                                     \
        const AS1 char* an = aBase + (size_t)(KS) * ACH_B;                  \
        const AS1 char* wn = wBase + (size_t)(KS) * (4 * WCH_B);            \
        _Pragma("unroll")                                                   \
        for (int f = 0; f < 10; ++f)                                        \
            AB[f] = *(const AS1 short8*)(an + f * 1024);                    \
        _Pragma("unroll")                                                   \
        for (int f = 0; f < 16; ++f)                                        \
            WB[f] = *(const AS1 short8*)(wn + f * 1024);                    \
    }

#define GEMM_MFMAS(AB, WB)                                                  \
    _Pragma("unroll")                                                       \
    for (int mt = 0; mt < 5; ++mt) {                                        \
        _Pragma("unroll")                                                   \
        for (int nt = 0; nt < 8; ++nt) {                                    \
            d[mt][nt] = __builtin_amdgcn_mfma_f32_16x16x32_bf16(            \
                AB[mt * 2 + 0], WB[nt * 2 + 0], d[mt][nt], 0, 0, 0);        \
            d[mt][nt] = __builtin_amdgcn_mfma_f32_16x16x32_bf16(            \
                AB[mt * 2 + 0], WB[nt * 2 + 1], d[mt][nt], 0, 0, 0);        \
            d[mt][nt] = __builtin_amdgcn_mfma_f32_16x16x32_bf16(            \
                AB[mt * 2 + 1], WB[nt * 2 + 0], d[mt][nt], 0, 0, 0);        \
        }                                                                   \
    }

__global__ __launch_bounds__(256, 1)
void gemm_kernel(const ushort* __restrict__ Ag,
                 const ushort* __restrict__ Wg,
                 float*       __restrict__ S1,       // (V,512) partial, khalf 0
                 float*       __restrict__ S2,       // (V,512) partial, khalf 1
                 int mg0) {
    const int b = blockIdx.x;
    const int mgl   = b >> 1;
    const int khalf = b & 1;
    const int Mbase = (mg0 + mgl) * 80;
    const int x = threadIdx.x;
    const int wj   = x >> 6;          // wave -> strip
    const int lane = x & 63;
    const int l16  = lane & 15;
    const int q    = lane >> 4;
    const int ks0   = khalf * KSPLIT;
    const int ksend = ks0 + KSPLIT;

    f32x4 d[5][8] = {};               // 160 f32 accumulators

    // Per-lane fragment base pointers (frag = contiguous 1 KB, lane*16 B).
    const AS1 char* aBase = (const AS1 char*)Ag
        + (size_t)mgl * NKSTEPS * ACH_B + lane * 16;
    const AS1 char* wBase = (const AS1 char*)Wg
        + (size_t)wj * WCH_B + lane * 16;

    short8 A0[10], W0[16], A1[10], W1[16];

    GEMM_LOADS(A0, W0, ks0);          // prologue -> buffer 0

    for (int ks = ks0; ks < ksend; ks += 2) {
        GEMM_LOADS(A1, W1, ks + 1);   // in flight while consuming buf 0
        GEMM_MFMAS(A0, W0);
        GEMM_LOADS(A0, W0, ks + 2);   // in flight while consuming buf 1
        GEMM_MFMAS(A1, W1);
    }

    // ---- epilogue: store raw partial (no bias) to this half's S buffer ----
    float* Sh = khalf ? S2 : S1;
    #pragma unroll
    for (int mt = 0; mt < 5; ++mt) {
        #pragma unroll
        for (int nt = 0; nt < 8; ++nt) {
            #pragma unroll
            for (int r = 0; r < 4; ++r) {
                const int mglob = Mbase + mt * 16 + q * 4 + r;
                const int nglob = wj * 128 + nt * 16 + l16;
                Sh[(size_t)mglob * 512 + nglob] = d[mt][nt][r];
            }
        }
    }
}

// ---------------------------------------------------------------------------
// Combine partials + bias, angular max-pool + BN (+residual) + ReLU.
// One wave per vertex: lane = t, loop over the 8 o's; butterfly norm reduce.
template<bool RES>
__global__ void pool_kernel(const float* __restrict__ S1,
                            const float* __restrict__ S2,
                            const float* __restrict__ bias,
                            const float* __restrict__ gamma,
                            const float* __restrict__ beta,
                            const float* __restrict__ resid,
                            float*       __restrict__ dst) {
    const int w = threadIdx.x >> 6;           // wave 0..3
    const int t = threadIdx.x & 63;
    const int v = blockIdx.x * 4 + w;         // grid 2500 -> 10000 vertices
    const float bt = bias[t];
    float vals[8], n2[8];
    #pragma unroll
    for (int o = 0; o < 8; ++o) {
        const size_t idx = (size_t)v * 512 + o * 64 + t;
        const float val = S1[idx] + S2[idx] + bt;
        vals[o] = val;
        float s = val * val;
        #pragma unroll
        for (int off = 1; off < 64; off <<= 1) s += __shfl_xor(s, off, 64);
        n2[o] = s;
    }
    int bj = 0; float bv = n2[0];
    #pragma unroll
    for (int j = 1; j < 8; ++j) {
        if (n2[j] > bv) { bv = n2[j]; bj = j; }   // first-max tie-break (jnp.argmax)
    }
    float val = vals[0];
    #pragma unroll
    for (int j = 1; j < 8; ++j) val = (bj == j) ? vals[j] : val;
    float r = gamma[t] * (val * BN_INV) + beta[t];
    if (RES) r += resid[(size_t)v * 64 + t];
    dst[(size_t)v * 64 + t] = fmaxf(r, 0.0f);
}

// ---------------------------------------------------------------------------
extern "C" void kernel_launch(void* const* d_in, const int* in_sizes, int n_in,
                              void* d_out, int out_size, void* d_ws, size_t ws_size,
                              hipStream_t stream) {
    const float* signal = (const float*)d_in[0];
    const float* bc_w   = (const float*)d_in[1];
    const float* t1     = (const float*)d_in[2];
    const float* bias1  = (const float*)d_in[3];
    const float* gamma1 = (const float*)d_in[4];
    const float* beta1  = (const float*)d_in[5];
    const float* t2     = (const float*)d_in[6];
    const float* bias2  = (const float*)d_in[7];
    const float* gamma2 = (const float*)d_in[8];
    const float* beta2  = (const float*)d_in[9];
    const int*   bc_idx = (const int*)d_in[10];

    // ws: W1g 5.24 | W2g 5.24 | S1 20.48 | S2 20.48 | s1 2.56 | Ag (rest) MB
    const size_t WSTG = (size_t)NKSTEPS * 4 * 8192;       // ushorts per stage W
    ushort* W1g = (ushort*)d_ws;
    ushort* W2g = W1g + WSTG;
    float* S1 = (float*)(W2g + WSTG);
    float* S2 = S1 + (size_t)NVV * 512;
    float* s1 = S2 + (size_t)NVV * 512;
    ushort* Ag = (ushort*)(s1 + (size_t)NVV * 64);
    float* out = (float*)d_out;

    // pass-chunk the materialized interp to fit ws_size (full A = 102.4 MB)
    const size_t used  = (size_t)((char*)Ag - (char*)d_ws);
    const size_t avail = ws_size > used ? ws_size - used : 0;
    int P = (int)(avail / ((size_t)NKSTEPS * ACH_B));     // mgs per pass
    if (P > 125) P = 125;
    if (P < 1)  P = 1;

    build_w_kernel<<<dim3(2560, 2), 512, 0, stream>>>(t1, t2, W1g, W2g);

    // stage 1
    for (int mg0 = 0; mg0 < 125; mg0 += P) {
        const int Pp = (125 - mg0 < P) ? (125 - mg0) : P;
        interp_kernel<<<Pp * NKSTEPS, 256, 0, stream>>>(signal, bc_idx, bc_w, Ag, mg0);
        gemm_kernel<<<2 * Pp, 256, 0, stream>>>(Ag, W1g, S1, S2, mg0);
    }
    pool_kernel<false><<<2500, 256, 0, stream>>>(S1, S2, bias1, gamma1, beta1, nullptr, s1);

    // stage 2
    for (int mg0 = 0; mg0 < 125; mg0 += P) {
        const int Pp = (125 - mg0 < P) ? (125 - mg0) : P;
        interp_kernel<<<Pp * NKSTEPS, 256, 0, stream>>>(s1, bc_idx, bc_w, Ag, mg0);
        gemm_kernel<<<2 * Pp, 256, 0, stream>>>(Ag, W2g, S1, S2, mg0);
    }
    pool_kernel<true><<<2500, 256, 0, stream>>>(S1, S2, bias2, gamma2, beta2, signal, out);
}